// Round 7
// baseline (622.250 us; speedup 1.0000x reference)
//
#include <hip/hip_runtime.h>

#define N    8192
#define DT   768
#define DO   512
#define BM   256
#define BN   256
#define TI   (N / BM)   // 32
#define TJ   (N / BN)   // 32
#define NTILE (TI * (TI + 1) / 2)   // 528 upper-triangle tiles (528 % 8 == 0)
#define NSLOT 256                   // 128 row-slots + 124 col-slots (+pad)
#define PL    ((size_t)NSLOT * N)   // one SoA plane: 256*8192 floats = 8 MB
#define NKT   (DT / 32)             // 24 teacher K-steps
#define NKO   (DO / 32)             // 16 student K-steps

typedef __attribute__((ext_vector_type(8))) short   short8;   // 8 bf16 = 4 VGPRs
typedef __attribute__((ext_vector_type(4))) float   floatx4;

struct alignas(8) us4 { unsigned short x[4]; };

// round-to-nearest-even fp32 -> bf16
__device__ inline unsigned short f2bf(float x) {
    union { float f; unsigned int u; } v; v.f = x;
    unsigned int r = v.u + 0x7fffu + ((v.u >> 16) & 1u);
    return (unsigned short)(r >> 16);
}
__device__ inline float bf2f(unsigned short u) {
    union { unsigned int u; float f; } v; v.u = ((unsigned int)u) << 16;
    return v.f;
}

// async global->LDS, 16B per lane (global_load_lds_dwordx4)
__device__ inline void gl2lds16(const unsigned short* g, unsigned short* l) {
    __builtin_amdgcn_global_load_lds(
        (const __attribute__((address_space(1))) unsigned int*)(const void*)g,
        (__attribute__((address_space(3))) unsigned int*)(void*)l,
        16, 0, 0);
}

// stage one 256x32 A-tile and B-tile (bf16) into an LDS ring slot.
// LINEAR LDS dest; bank-conflict swizzle via permuted GLOBAL source chunk
// (within each row's 64B segment); matching XOR on the ds_read side.
// 512 threads x 2 iters -> 1024 x 16B per operand. 4 VMEM instrs per thread.
template <int D>
__device__ inline void stage_tile(const unsigned short* __restrict__ X,
                                  unsigned short* sAb, unsigned short* sBb,
                                  int i0, int j0, int k, int t) {
    #pragma unroll
    for (int h = 0; h < 2; ++h) {
        const int idx = t + h * 512;        // 0..1023
        const int r   = idx >> 2;           // 0..255
        const int cs  = ((idx & 3) ^ ((r >> 1) & 3)) << 3;   // swizzled col-chunk
        gl2lds16(X + (size_t)(i0 + r) * D + k + cs, &sAb[idx * 8]);
        gl2lds16(X + (size_t)(j0 + r) * D + k + cs, &sBb[idx * 8]);
    }
}

// fragment loads + 32 MFMA for one 32-wide K-step (per-wave 128x64 output)
__device__ inline void mfma_step(const unsigned short* __restrict__ sAb,
                                 const unsigned short* __restrict__ sBb,
                                 floatx4 (&acc)[8][4],
                                 int wm, int wn, int lr, int lgx) {
    short8 af[8], bf[4];
    #pragma unroll
    for (int mi = 0; mi < 8; ++mi)
        af[mi] = *(const short8*)&sAb[(wm * 128 + mi * 16 + lr) * 32 + (lgx << 3)];
    #pragma unroll
    for (int ni = 0; ni < 4; ++ni)
        bf[ni] = *(const short8*)&sBb[(wn * 64 + ni * 16 + lr) * 32 + (lgx << 3)];
    #pragma unroll
    for (int mi = 0; mi < 8; ++mi)
        #pragma unroll
        for (int ni = 0; ni < 4; ++ni)
            acc[mi][ni] = __builtin_amdgcn_mfma_f32_16x16x32_bf16(
                af[mi], bf[ni], acc[mi][ni], 0, 0, 0);
}

// bid -> (ti, tj) upper-triangle with bijective chunked XCD swizzle
__device__ inline void tile_coords(int bid, int& ti, int& tj) {
    const int swb = (bid & 7) * (NTILE / 8) + (bid >> 3);
    int rem = swb; int a = 0;
    while (rem >= TI - a) { rem -= TI - a; ++a; }
    ti = a; tj = a + rem;
}

// ---------------- row-normalize fp32 -> bf16 (one wave per row) ----------------
__global__ void norm_kernel(const float* __restrict__ Tg,
                            const float* __restrict__ Mo,
                            unsigned short* __restrict__ Xt,
                            unsigned short* __restrict__ Xo,
                            float* __restrict__ zero_me) {
    if (blockIdx.x == 0 && threadIdx.x == 0) zero_me[0] = 0.0f;
    int bid = blockIdx.x;
    const float* X; unsigned short* Xn; int D;
    if (bid < N / 4) { X = Tg; Xn = Xt; D = DT; }
    else             { bid -= N / 4; X = Mo; Xn = Xo; D = DO; }
    const int row  = bid * 4 + (threadIdx.x >> 6);
    const int lane = threadIdx.x & 63;
    const int nch  = D >> 8;                       // 3 (DT) or 2 (DO)
    const float* xr = X + (size_t)row * D;
    floatx4 vc[3];
    float ss = 0.0f;
    #pragma unroll
    for (int h = 0; h < 3; ++h) {
        if (h < nch) {
            vc[h] = *(const floatx4*)(xr + lane * 4 + h * 256);
            ss += vc[h][0] * vc[h][0] + vc[h][1] * vc[h][1]
                + vc[h][2] * vc[h][2] + vc[h][3] * vc[h][3];
        }
    }
    #pragma unroll
    for (int m = 32; m >= 1; m >>= 1) ss += __shfl_xor(ss, m);
    const float scale = 1.0f / fmaxf(sqrtf(ss), 1e-8f);
    unsigned short* outr = Xn + (size_t)row * D;
    #pragma unroll
    for (int h = 0; h < 3; ++h) {
        if (h < nch) {
            us4 o;
            #pragma unroll
            for (int j = 0; j < 4; ++j) o.x[j] = f2bf(vc[h][j] * scale);
            *(us4*)(outr + lane * 4 + h * 256) = o;
        }
    }
}

// ---------------- teacher kernel: 256^2 GEMM + Zt/V/UA stats + W -> global ----
// 8 waves (wm in {0,1}, wn in {0..3}), per-wave 128x64 output, acc[8][4].
// Ring-4 LDS (128 KB, 1 block/CU), lookahead-3, counted vmcnt, ONE barrier
// per K-step, setprio around MFMA cluster.
// Slots: row-sums -> tj*4+wn (0..127); col-sums -> 128 + ti*4 + wm*2 + (mi>=4).
// Per row i (tile a = i>>8) the written slots = contiguous [4a, 4a+128).
__launch_bounds__(512, 2)
__global__ void fused_t_kernel(const unsigned short* __restrict__ Xt,
                               float* __restrict__ partials,
                               unsigned int* __restrict__ Wws) {
    __shared__ unsigned short sA[4][BM * 32];     // 4 x 16 KB
    __shared__ unsigned short sB[4][BN * 32];     // 4 x 16 KB  (total 128 KB)

    const int t    = threadIdx.x;
    const int lane = t & 63;
    const int w    = t >> 6;
    const int wm   = w >> 2, wn = w & 3;
    const int lr   = lane & 15, lg = lane >> 4;
    const int lgx  = lg ^ ((lr >> 1) & 3);

    int ti, tj; tile_coords(blockIdx.x, ti, tj);
    const bool offdiag = (ti != tj);
    const int i0 = ti * BM, j0 = tj * BN;
    unsigned int* const wt = Wws + (size_t)blockIdx.x * 32768;   // 64 u32 x 512 thr

    floatx4 acc[8][4];
    #pragma unroll
    for (int a = 0; a < 8; ++a)
        #pragma unroll
        for (int b = 0; b < 4; ++b)
            acc[a][b] = (floatx4){0.0f, 0.0f, 0.0f, 0.0f};

    stage_tile<DT>(Xt, sA[0], sB[0], i0, j0, 0, t);
    stage_tile<DT>(Xt, sA[1], sB[1], i0, j0, 32, t);
    stage_tile<DT>(Xt, sA[2], sB[2], i0, j0, 64, t);

    for (int s = 0; s < NKT; ++s) {
        if (s + 2 < NKT)      asm volatile("s_waitcnt vmcnt(8)" ::: "memory");
        else if (s + 1 < NKT) asm volatile("s_waitcnt vmcnt(4)" ::: "memory");
        else                  asm volatile("s_waitcnt vmcnt(0)" ::: "memory");
        __builtin_amdgcn_s_barrier();
        asm volatile("" ::: "memory");
        if (s + 3 < NKT)
            stage_tile<DT>(Xt, sA[(s + 3) & 3], sB[(s + 3) & 3], i0, j0, (s + 3) * 32, t);
        __builtin_amdgcn_s_setprio(1);
        mfma_step(sA[s & 3], sB[s & 3], acc, wm, wn, lr, lgx);
        __builtin_amdgcn_s_setprio(0);
        asm volatile("" ::: "memory");
    }

    // ---- epilogue. C/D layout: col = lane&15, row = (lane>>4)*4 + reg ----
    {
        float czt[2][4], cvv[2][4], cua[2][4];
        #pragma unroll
        for (int hh = 0; hh < 2; ++hh)
            #pragma unroll
            for (int ni = 0; ni < 4; ++ni) {
                czt[hh][ni] = 0.0f; cvv[hh][ni] = 0.0f; cua[hh][ni] = 0.0f;
            }
        #pragma unroll
        for (int mi = 0; mi < 8; ++mi) {
            unsigned int wpk[4][2];                        // [ni][r>>1] bf16 pairs
            #pragma unroll
            for (int r = 0; r < 4; ++r) {
                const int row = wm * 128 + mi * 16 + lg * 4 + r;
                const int gi  = i0 + row;
                float zt = 0.0f, vv = 0.0f, ua = 0.0f;
                #pragma unroll
                for (int ni = 0; ni < 4; ++ni) {
                    const int gj = j0 + wn * 64 + ni * 16 + lr;
                    const float a = acc[mi][ni][r];
                    float ea = __expf(a - 1.0f);
                    if (gi == gj) ea = 0.0f;               // diagonal -> prob 0
                    const float e3 = ea * ea * ea;
                    zt += ea; vv += e3; ua += e3 * a;
                    czt[mi >> 2][ni] += ea; cvv[mi >> 2][ni] += e3;
                    cua[mi >> 2][ni] += e3 * a;
                    if ((r & 1) == 0) wpk[ni][r >> 1]  = (unsigned int)f2bf(e3);
                    else              wpk[ni][r >> 1] |= ((unsigned int)f2bf(e3)) << 16;
                }
                #pragma unroll
                for (int m = 8; m >= 1; m >>= 1) {
                    zt += __shfl_xor(zt, m);
                    vv += __shfl_xor(vv, m);
                    ua += __shfl_xor(ua, m);
                }
                if (lr == 0) {
                    const size_t base = (size_t)(tj * 4 + wn) * N + gi;
                    partials[0 * PL + base] = zt;
                    partials[1 * PL + base] = vv;
                    partials[2 * PL + base] = ua;
                }
            }
            #pragma unroll
            for (int ni = 0; ni < 4; ++ni)
                #pragma unroll
                for (int rp = 0; rp < 2; ++rp)
                    wt[(mi * 8 + ni * 2 + rp) * 512 + t] = wpk[ni][rp];   // coalesced
        }
        if (offdiag) {
            #pragma unroll
            for (int hh = 0; hh < 2; ++hh)
                #pragma unroll
                for (int ni = 0; ni < 4; ++ni) {
                    #pragma unroll
                    for (int m = 16; m <= 32; m <<= 1) {
                        czt[hh][ni] += __shfl_xor(czt[hh][ni], m);
                        cvv[hh][ni] += __shfl_xor(cvv[hh][ni], m);
                        cua[hh][ni] += __shfl_xor(cua[hh][ni], m);
                    }
                }
            if (lg == 0) {
                #pragma unroll
                for (int hh = 0; hh < 2; ++hh)
                    #pragma unroll
                    for (int ni = 0; ni < 4; ++ni) {
                        const int gj = j0 + wn * 64 + ni * 16 + lr;   // contiguous
                        const size_t base =
                            (size_t)(128 + ti * 4 + wm * 2 + hh) * N + gj;
                        partials[0 * PL + base] = czt[hh][ni];
                        partials[1 * PL + base] = cvv[hh][ni];
                        partials[2 * PL + base] = cua[hh][ni];
                    }
            }
        }
    }
}

// ---------------- student kernel: 256^2 GEMM + Zo/WB stats (W from global) ----
__launch_bounds__(512, 2)
__global__ void fused_o_kernel(const unsigned short* __restrict__ Xo,
                               float* __restrict__ partials,
                               const unsigned int* __restrict__ Wws) {
    __shared__ unsigned short sA[4][BM * 32];
    __shared__ unsigned short sB[4][BN * 32];

    const int t    = threadIdx.x;
    const int lane = t & 63;
    const int w    = t >> 6;
    const int wm   = w >> 2, wn = w & 3;
    const int lr   = lane & 15, lg = lane >> 4;
    const int lgx  = lg ^ ((lr >> 1) & 3);

    int ti, tj; tile_coords(blockIdx.x, ti, tj);
    const bool offdiag = (ti != tj);
    const int i0 = ti * BM, j0 = tj * BN;
    const unsigned int* const wt = Wws + (size_t)blockIdx.x * 32768;

    floatx4 acc[8][4];
    #pragma unroll
    for (int a = 0; a < 8; ++a)
        #pragma unroll
        for (int b = 0; b < 4; ++b)
            acc[a][b] = (floatx4){0.0f, 0.0f, 0.0f, 0.0f};

    stage_tile<DO>(Xo, sA[0], sB[0], i0, j0, 0, t);
    stage_tile<DO>(Xo, sA[1], sB[1], i0, j0, 32, t);
    stage_tile<DO>(Xo, sA[2], sB[2], i0, j0, 64, t);

    for (int s = 0; s < NKO; ++s) {
        if (s + 2 < NKO)      asm volatile("s_waitcnt vmcnt(8)" ::: "memory");
        else if (s + 1 < NKO) asm volatile("s_waitcnt vmcnt(4)" ::: "memory");
        else                  asm volatile("s_waitcnt vmcnt(0)" ::: "memory");
        __builtin_amdgcn_s_barrier();
        asm volatile("" ::: "memory");
        if (s + 3 < NKO)
            stage_tile<DO>(Xo, sA[(s + 3) & 3], sB[(s + 3) & 3], i0, j0, (s + 3) * 32, t);
        __builtin_amdgcn_s_setprio(1);
        mfma_step(sA[s & 3], sB[s & 3], acc, wm, wn, lr, lgx);
        __builtin_amdgcn_s_setprio(0);
        asm volatile("" ::: "memory");
    }

    // ---- epilogue: Zo, Sum(W*b). W loaded in two 32-reg chunks to cap VGPRs. ----
    {
        float czo[2][4], cwb[2][4];
        #pragma unroll
        for (int hh = 0; hh < 2; ++hh)
            #pragma unroll
            for (int ni = 0; ni < 4; ++ni) { czo[hh][ni] = 0.0f; cwb[hh][ni] = 0.0f; }
        #pragma unroll
        for (int half = 0; half < 2; ++half) {
            unsigned int wld[32];
            #pragma unroll
            for (int pi = 0; pi < 32; ++pi)
                wld[pi] = wt[(half * 32 + pi) * 512 + t];   // coalesced
            #pragma unroll
            for (int mq = 0; mq < 4; ++mq) {
                const int mi = half * 4 + mq;
                #pragma unroll
                for (int r = 0; r < 4; ++r) {
                    const int row = wm * 128 + mi * 16 + lg * 4 + r;
                    const int gi  = i0 + row;
                    float zo = 0.0f, wb = 0.0f;
                    #pragma unroll
                    for (int ni = 0; ni < 4; ++ni) {
                        const int gj = j0 + wn * 64 + ni * 16 + lr;
                        const float b = acc[mi][ni][r];
                        float eb = __expf(b - 1.0f);
                        if (gi == gj) eb = 0.0f;
                        const unsigned int pw = wld[mq * 8 + ni * 2 + (r >> 1)];
                        const float wgt = bf2f((unsigned short)((r & 1) ? (pw >> 16)
                                                                        : (pw & 0xffffu)));
                        zo += eb; wb += wgt * b;   // diag: W==0 -> no contribution
                        czo[half][ni] += eb; cwb[half][ni] += wgt * b;
                    }
                    #pragma unroll
                    for (int m = 8; m >= 1; m >>= 1) {
                        zo += __shfl_xor(zo, m);
                        wb += __shfl_xor(wb, m);
                    }
                    if (lr == 0) {
                        const size_t base = (size_t)(tj * 4 + wn) * N + gi;
                        partials[3 * PL + base] = zo;
                        partials[4 * PL + base] = wb;
                    }
                }
            }
        }
        if (offdiag) {
            #pragma unroll
            for (int hh = 0; hh < 2; ++hh)
                #pragma unroll
                for (int ni = 0; ni < 4; ++ni) {
                    #pragma unroll
                    for (int m = 16; m <= 32; m <<= 1) {
                        czo[hh][ni] += __shfl_xor(czo[hh][ni], m);
                        cwb[hh][ni] += __shfl_xor(cwb[hh][ni], m);
                    }
                }
            if (lg == 0) {
                #pragma unroll
                for (int hh = 0; hh < 2; ++hh)
                    #pragma unroll
                    for (int ni = 0; ni < 4; ++ni) {
                        const int gj = j0 + wn * 64 + ni * 16 + lr;
                        const size_t base =
                            (size_t)(128 + ti * 4 + wm * 2 + hh) * N + gj;
                        partials[3 * PL + base] = czo[hh][ni];
                        partials[4 * PL + base] = cwb[hh][ni];
                    }
            }
        }
    }
}

// ---------------- final per-row combine + scalar reduce ----------------
// Row i belongs to tile a = i>>8; its 128 written slots are the contiguous
// window [4a, 4a+128). 128 blocks x 64 rows; 4 waves split the window.
__global__ void reduce_kernel(const float* __restrict__ partials,
                              float* __restrict__ out) {
    __shared__ float sh[5][256];
    const int t    = threadIdx.x;
    const int lane = t & 63;
    const int g    = t >> 6;
    const int i    = blockIdx.x * 64 + lane;      // row (coalesced across lanes)
    const int w0   = (blockIdx.x >> 2) * 4;       // = 4*(i>>8), uniform per block
    float s[5] = {0.0f, 0.0f, 0.0f, 0.0f, 0.0f};
    for (int u = g * 32; u < g * 32 + 32; ++u) {
        const size_t base = (size_t)(w0 + u) * N + i;
        #pragma unroll
        for (int p = 0; p < 5; ++p) s[p] += partials[p * PL + base];
    }
    #pragma unroll
    for (int p = 0; p < 5; ++p) sh[p][t] = s[p];
    __syncthreads();
    if (g == 0) {
        float v[5];
        #pragma unroll
        for (int p = 0; p < 5; ++p)
            v[p] = sh[p][lane] + sh[p][64 + lane] + sh[p][128 + lane] + sh[p][192 + lane];
        // loss_i = (UA - WB + V*log(Zo/Zt)) / Zt^3
        float li = (v[2] - v[4] + v[1] * __logf(v[3] / v[0])) / (v[0] * v[0] * v[0]);
        #pragma unroll
        for (int m = 32; m >= 1; m >>= 1) li += __shfl_xor(li, m);
        if (lane == 0)
            atomicAdd(out, li * (1.0f / ((float)N * (float)N)));   // WEIGHT=1
    }
}

extern "C" void kernel_launch(void* const* d_in, const int* in_sizes, int n_in,
                              void* d_out, int out_size, void* d_ws, size_t ws_size,
                              hipStream_t stream) {
    (void)in_sizes; (void)n_in; (void)out_size; (void)ws_size;
    const float* mo = (const float*)d_in[0];   // model_output [8192,512] fp32
    const float* tg = (const float*)d_in[1];   // targets      [8192,768] fp32
    float* out = (float*)d_out;

    char* ws = (char*)d_ws;
    unsigned short* Xt = (unsigned short*)ws;                          // 12.58 MB
    unsigned short* Xo = (unsigned short*)(ws + (size_t)N * DT * 2);   //  8.39 MB
    float* partials    = (float*)(ws + (size_t)N * DT * 2 + (size_t)N * DO * 2);
    // partials: 5 planes * 256 * 8192 * 4 B = 41.9 MB
    unsigned int* Wws  = (unsigned int*)((char*)partials + 5 * PL * sizeof(float));
    // Wws: 528 tiles * 32768 u32 * 4 B = 66.1 MB; total ws use ~129 MB

    norm_kernel<<<2 * (N / 4), 256, 0, stream>>>(tg, mo, Xt, Xo, out);  // also zeroes out
    fused_t_kernel<<<NTILE, 512, 0, stream>>>(Xt, partials, Wws);
    fused_o_kernel<<<NTILE, 512, 0, stream>>>(Xo, partials, Wws);
    reduce_kernel<<<N / 64, 256, 0, stream>>>(partials, out);
}

// Round 8
// 320.927 us; speedup vs baseline: 1.9389x; 1.9389x over previous
//
#include <hip/hip_runtime.h>

#define N    8192
#define DT   768
#define DO   512
#define BM   128
#define BN   128
#define TI   (N / BM)   // 64
#define TJ   (N / BN)   // 64
#define NTILE (TI * (TI + 1) / 2)   // 2080 upper-triangle tiles (2080 % 8 == 0)
#define NSLOT (2 * TJ)              // 128 partial slots per row
#define PL    ((size_t)NSLOT * N)   // one SoA plane: 128*8192 floats = 4 MB
#define NKT   (DT / 32)             // 24 teacher K-steps
#define NKO   (DO / 32)             // 16 student K-steps

typedef __attribute__((ext_vector_type(8))) short   short8;   // 8 bf16 = 4 VGPRs
typedef __attribute__((ext_vector_type(4))) float   floatx4;

struct alignas(8) us4 { unsigned short x[4]; };

// round-to-nearest-even fp32 -> bf16
__device__ inline unsigned short f2bf(float x) {
    union { float f; unsigned int u; } v; v.f = x;
    unsigned int r = v.u + 0x7fffu + ((v.u >> 16) & 1u);
    return (unsigned short)(r >> 16);
}
__device__ inline float bf2f(unsigned short u) {
    union { unsigned int u; float f; } v; v.u = ((unsigned int)u) << 16;
    return v.f;
}

// async global->LDS, 16B per lane (global_load_lds_dwordx4)
__device__ inline void gl2lds16(const unsigned short* g, unsigned short* l) {
    __builtin_amdgcn_global_load_lds(
        (const __attribute__((address_space(1))) unsigned int*)(const void*)g,
        (__attribute__((address_space(3))) unsigned int*)(void*)l,
        16, 0, 0);
}

// stage one 128x32 A-tile and B-tile (bf16) into an LDS ring slot.
// LDS destination LINEAR (global_load_lds writes base+lane*16); bank-conflict
// swizzle applied by permuting the GLOBAL source column chunk; matching XOR
// on the ds_read side (2-way residual = free). 4 VMEM instrs per thread.
template <int D>
__device__ inline void stage_tile(const unsigned short* __restrict__ X,
                                  unsigned short* sAb, unsigned short* sBb,
                                  int i0, int j0, int k, int t) {
    #pragma unroll
    for (int h = 0; h < 2; ++h) {
        const int idx = t + h * 256;        // 0..511; lane-contiguous per wave
        const int r   = idx >> 2;
        const int cs  = ((idx & 3) ^ ((r >> 1) & 3)) << 3;   // swizzled col-chunk
        gl2lds16(X + (size_t)(i0 + r) * D + k + cs, &sAb[idx * 8]);
        gl2lds16(X + (size_t)(j0 + r) * D + k + cs, &sBb[idx * 8]);
    }
}

// fragment loads + 16 MFMA for one 32-wide K-step
__device__ inline void mfma_step(const unsigned short* __restrict__ sAb,
                                 const unsigned short* __restrict__ sBb,
                                 floatx4 (&acc)[4][4],
                                 int wm, int wn, int lr, int lgx) {
    short8 af[4], bf[4];
    #pragma unroll
    for (int mi = 0; mi < 4; ++mi)
        af[mi] = *(const short8*)&sAb[(wm * 64 + mi * 16 + lr) * 32 + (lgx << 3)];
    #pragma unroll
    for (int ni = 0; ni < 4; ++ni)
        bf[ni] = *(const short8*)&sBb[(wn * 64 + ni * 16 + lr) * 32 + (lgx << 3)];
    #pragma unroll
    for (int mi = 0; mi < 4; ++mi)
        #pragma unroll
        for (int ni = 0; ni < 4; ++ni)
            acc[mi][ni] = __builtin_amdgcn_mfma_f32_16x16x32_bf16(
                af[mi], bf[ni], acc[mi][ni], 0, 0, 0);
}

// bid -> (ti, tj): chunked XCD swizzle + SUPER-BLOCK enumeration (R8).
// The triangle of 64x64 tiles is partitioned into 8x8 super-blocks (SBs):
// diagonal SBs hold 36 tiles, off-diagonal 64 (8*36 + 28*64 = 2080).
// Enumeration: SBs in (sti, stj>=sti) row-major order; tiles row-major within.
// Each XCD's contiguous 260-rank chunk then spans ~4 SBs, so its ~32 in-flight
// blocks touch <= 4 A-panels + 8 B-panels (~2.3 MB) -> both operands L2-hit
// (R6's row-run order spanned ~32 B-panels = 6 MB -> B missed L2 every stage).
__device__ inline void tile_coords(int bid, int& ti, int& tj) {
    int swb = (bid & 7) * (NTILE / 8) + (bid >> 3);   // contiguous per XCD
    int sti = 0, stj = 0;
    for (;;) {
        const int sz = (sti == stj) ? 36 : 64;
        if (swb < sz) break;
        swb -= sz;
        if (++stj == 8) { ++sti; stj = sti; }
    }
    int i, j;
    if (sti == stj) {            // triangular SB: row i has 8-i tiles (j >= i)
        i = 0;
        while (swb >= 8 - i) { swb -= 8 - i; ++i; }
        j = i + swb;
    } else {                     // full SB: row-major 8x8
        i = swb >> 3;
        j = swb & 7;
    }
    ti = sti * 8 + i;
    tj = stj * 8 + j;
}

// ---------------- row-normalize fp32 -> bf16 (one wave per row) ----------------
__global__ void norm_kernel(const float* __restrict__ Tg,
                            const float* __restrict__ Mo,
                            unsigned short* __restrict__ Xt,
                            unsigned short* __restrict__ Xo,
                            float* __restrict__ zero_me) {
    if (blockIdx.x == 0 && threadIdx.x == 0) zero_me[0] = 0.0f;
    int bid = blockIdx.x;
    const float* X; unsigned short* Xn; int D;
    if (bid < N / 4) { X = Tg; Xn = Xt; D = DT; }
    else             { bid -= N / 4; X = Mo; Xn = Xo; D = DO; }
    const int row  = bid * 4 + (threadIdx.x >> 6);
    const int lane = threadIdx.x & 63;
    const int nch  = D >> 8;                       // 3 (DT) or 2 (DO)
    const float* xr = X + (size_t)row * D;
    floatx4 vc[3];
    float ss = 0.0f;
    #pragma unroll
    for (int h = 0; h < 3; ++h) {
        if (h < nch) {
            vc[h] = *(const floatx4*)(xr + lane * 4 + h * 256);
            ss += vc[h][0] * vc[h][0] + vc[h][1] * vc[h][1]
                + vc[h][2] * vc[h][2] + vc[h][3] * vc[h][3];
        }
    }
    #pragma unroll
    for (int m = 32; m >= 1; m >>= 1) ss += __shfl_xor(ss, m);
    const float scale = 1.0f / fmaxf(sqrtf(ss), 1e-8f);
    unsigned short* outr = Xn + (size_t)row * D;
    #pragma unroll
    for (int h = 0; h < 3; ++h) {
        if (h < nch) {
            us4 o;
            #pragma unroll
            for (int j = 0; j < 4; ++j) o.x[j] = f2bf(vc[h][j] * scale);
            *(us4*)(outr + lane * 4 + h * 256) = o;
        }
    }
}

// ---------------- teacher kernel: GEMM + Zt/V/UA stats + W -> global ----------
// Single acc (64 f32) -> 3 blocks/CU (12 waves), ring-3 LDS (48 KB),
// lookahead-2, ONE barrier per K-step, counted vmcnt(4) (never 0 mid-loop).
// Safety: vmcnt(4) at iter s => own stage(s) landed (stage(s+1)'s 4 instrs may
// remain); barrier publishes for all waves. stage(s+2) (issued post-barrier)
// overwrites slot (s-1)%3, whose reads completed before this barrier.
__launch_bounds__(256, 3)
__global__ void fused_t_kernel(const unsigned short* __restrict__ Xt,
                               float* __restrict__ partials,
                               unsigned int* __restrict__ Wws) {
    __shared__ unsigned short sA[3][BM * 32];     // 3 x 8 KB
    __shared__ unsigned short sB[3][BN * 32];     // 3 x 8 KB   (total 48 KB)

    const int t    = threadIdx.x;
    const int lane = t & 63;
    const int w    = t >> 6;
    const int wm   = w >> 1, wn = w & 1;
    const int lr   = lane & 15, lg = lane >> 4;
    const int lgx  = lg ^ ((lr >> 1) & 3);

    int ti, tj; tile_coords(blockIdx.x, ti, tj);
    const bool offdiag = (ti != tj);
    const int i0 = ti * BM, j0 = tj * BN;
    unsigned int* const wt = Wws + (size_t)blockIdx.x * 8192;

    floatx4 acc[4][4];
    #pragma unroll
    for (int a = 0; a < 4; ++a)
        #pragma unroll
        for (int b = 0; b < 4; ++b)
            acc[a][b] = (floatx4){0.0f, 0.0f, 0.0f, 0.0f};

    stage_tile<DT>(Xt, sA[0], sB[0], i0, j0, 0, t);
    stage_tile<DT>(Xt, sA[1], sB[1], i0, j0, 32, t);

    for (int s = 0; s < NKT; ++s) {
        if (s + 1 < NKT) asm volatile("s_waitcnt vmcnt(4)" ::: "memory");
        else             asm volatile("s_waitcnt vmcnt(0)" ::: "memory");
        __builtin_amdgcn_s_barrier();
        asm volatile("" ::: "memory");
        if (s + 2 < NKT)
            stage_tile<DT>(Xt, sA[(s + 2) % 3], sB[(s + 2) % 3], i0, j0, (s + 2) * 32, t);
        mfma_step(sA[s % 3], sB[s % 3], acc, wm, wn, lr, lgx);
        asm volatile("" ::: "memory");
    }

    // ---- epilogue: Zt, V, Sum(e3*a) per row (both orientations); W packed ----
    // C/D layout: col = lane&15, row = (lane>>4)*4 + reg
    {
        float czt[4], cvv[4], cua[4];
        #pragma unroll
        for (int ni = 0; ni < 4; ++ni) { czt[ni] = 0.0f; cvv[ni] = 0.0f; cua[ni] = 0.0f; }
        #pragma unroll
        for (int mi = 0; mi < 4; ++mi) {
            unsigned int wpk[4][2];                        // [ni][r>>1] bf16 pairs
            #pragma unroll
            for (int r = 0; r < 4; ++r) {
                const int row = wm * 64 + mi * 16 + lg * 4 + r;
                const int gi  = i0 + row;
                float zt = 0.0f, vv = 0.0f, ua = 0.0f;
                #pragma unroll
                for (int ni = 0; ni < 4; ++ni) {
                    const int gj = j0 + wn * 64 + ni * 16 + lr;
                    const float a = acc[mi][ni][r];
                    float ea = __expf(a - 1.0f);
                    if (gi == gj) ea = 0.0f;               // diagonal -> prob 0
                    const float e3 = ea * ea * ea;
                    zt += ea; vv += e3; ua += e3 * a;
                    czt[ni] += ea; cvv[ni] += e3; cua[ni] += e3 * a;
                    if ((r & 1) == 0) wpk[ni][r >> 1]  = (unsigned int)f2bf(e3);
                    else              wpk[ni][r >> 1] |= ((unsigned int)f2bf(e3)) << 16;
                }
                #pragma unroll
                for (int m = 8; m >= 1; m >>= 1) {
                    zt += __shfl_xor(zt, m);
                    vv += __shfl_xor(vv, m);
                    ua += __shfl_xor(ua, m);
                }
                if (lr == 0) {
                    const size_t base = (size_t)(tj * 2 + wn) * N + gi;
                    partials[0 * PL + base] = zt;
                    partials[1 * PL + base] = vv;
                    partials[2 * PL + base] = ua;
                }
            }
            #pragma unroll
            for (int ni = 0; ni < 4; ++ni)
                #pragma unroll
                for (int rp = 0; rp < 2; ++rp)
                    wt[(mi * 8 + ni * 2 + rp) * 256 + t] = wpk[ni][rp];   // coalesced
        }
        if (offdiag) {
            #pragma unroll
            for (int ni = 0; ni < 4; ++ni) {
                #pragma unroll
                for (int m = 16; m <= 32; m <<= 1) {
                    czt[ni] += __shfl_xor(czt[ni], m);
                    cvv[ni] += __shfl_xor(cvv[ni], m);
                    cua[ni] += __shfl_xor(cua[ni], m);
                }
            }
            if (lg == 0) {
                #pragma unroll
                for (int ni = 0; ni < 4; ++ni) {
                    const int gj = j0 + wn * 64 + ni * 16 + lr;   // contiguous in lr
                    const size_t base = (size_t)(ti * 2 + wm) * N + gj;
                    partials[0 * PL + base] = czt[ni];
                    partials[1 * PL + base] = cvv[ni];
                    partials[2 * PL + base] = cua[ni];
                }
            }
        }
    }
}

// ---------------- student kernel: GEMM + Zo/WB stats (W from global) ---------
__launch_bounds__(256, 3)
__global__ void fused_o_kernel(const unsigned short* __restrict__ Xo,
                               float* __restrict__ partials,
                               const unsigned int* __restrict__ Wws) {
    __shared__ unsigned short sA[3][BM * 32];
    __shared__ unsigned short sB[3][BN * 32];

    const int t    = threadIdx.x;
    const int lane = t & 63;
    const int w    = t >> 6;
    const int wm   = w >> 1, wn = w & 1;
    const int lr   = lane & 15, lg = lane >> 4;
    const int lgx  = lg ^ ((lr >> 1) & 3);

    int ti, tj; tile_coords(blockIdx.x, ti, tj);
    const bool offdiag = (ti != tj);
    const int i0 = ti * BM, j0 = tj * BN;
    const unsigned int* const wt = Wws + (size_t)blockIdx.x * 8192;

    floatx4 acc[4][4];
    #pragma unroll
    for (int a = 0; a < 4; ++a)
        #pragma unroll
        for (int b = 0; b < 4; ++b)
            acc[a][b] = (floatx4){0.0f, 0.0f, 0.0f, 0.0f};

    stage_tile<DO>(Xo, sA[0], sB[0], i0, j0, 0, t);
    stage_tile<DO>(Xo, sA[1], sB[1], i0, j0, 32, t);

    for (int s = 0; s < NKO; ++s) {
        if (s + 1 < NKO) asm volatile("s_waitcnt vmcnt(4)" ::: "memory");
        else             asm volatile("s_waitcnt vmcnt(0)" ::: "memory");
        __builtin_amdgcn_s_barrier();
        asm volatile("" ::: "memory");
        if (s + 2 < NKO)
            stage_tile<DO>(Xo, sA[(s + 2) % 3], sB[(s + 2) % 3], i0, j0, (s + 2) * 32, t);
        mfma_step(sA[s % 3], sB[s % 3], acc, wm, wn, lr, lgx);
        asm volatile("" ::: "memory");
    }

    // ---- epilogue: Zo, Sum(W*b) per row (both orientations). W loads issued
    //      up-front; their L2/L3 latency hides under the exp/stat VALU. ----
    {
        unsigned int wld[32];
        #pragma unroll
        for (int pi = 0; pi < 32; ++pi)
            wld[pi] = wt[pi * 256 + t];        // coalesced; same-XCD L2 mostly
        float czo[4], cwb[4];
        #pragma unroll
        for (int ni = 0; ni < 4; ++ni) { czo[ni] = 0.0f; cwb[ni] = 0.0f; }
        #pragma unroll
        for (int mi = 0; mi < 4; ++mi) {
            #pragma unroll
            for (int r = 0; r < 4; ++r) {
                const int row = wm * 64 + mi * 16 + lg * 4 + r;
                const int gi  = i0 + row;
                float zo = 0.0f, wb = 0.0f;
                #pragma unroll
                for (int ni = 0; ni < 4; ++ni) {
                    const int gj = j0 + wn * 64 + ni * 16 + lr;
                    const float b = acc[mi][ni][r];
                    float eb = __expf(b - 1.0f);
                    if (gi == gj) eb = 0.0f;
                    const unsigned int pw = wld[mi * 8 + ni * 2 + (r >> 1)];
                    const float wgt = bf2f((unsigned short)((r & 1) ? (pw >> 16)
                                                                    : (pw & 0xffffu)));
                    zo += eb; wb += wgt * b;   // diag: W==0 -> no contribution
                    czo[ni] += eb; cwb[ni] += wgt * b;
                }
                #pragma unroll
                for (int m = 8; m >= 1; m >>= 1) {
                    zo += __shfl_xor(zo, m);
                    wb += __shfl_xor(wb, m);
                }
                if (lr == 0) {
                    const size_t base = (size_t)(tj * 2 + wn) * N + gi;
                    partials[3 * PL + base] = zo;
                    partials[4 * PL + base] = wb;
                }
            }
        }
        if (offdiag) {
            #pragma unroll
            for (int ni = 0; ni < 4; ++ni) {
                #pragma unroll
                for (int m = 16; m <= 32; m <<= 1) {
                    czo[ni] += __shfl_xor(czo[ni], m);
                    cwb[ni] += __shfl_xor(cwb[ni], m);
                }
            }
            if (lg == 0) {
                #pragma unroll
                for (int ni = 0; ni < 4; ++ni) {
                    const int gj = j0 + wn * 64 + ni * 16 + lr;
                    const size_t base = (size_t)(ti * 2 + wm) * N + gj;
                    partials[3 * PL + base] = czo[ni];
                    partials[4 * PL + base] = cwb[ni];
                }
            }
        }
    }
}

// ---------------- final per-row combine + scalar reduce ----------------
__global__ void reduce_kernel(const float* __restrict__ partials,
                              float* __restrict__ out) {
    __shared__ float sh[5][256];
    const int t    = threadIdx.x;
    const int lane = t & 63;
    const int g    = t >> 6;
    const int i    = blockIdx.x * 64 + lane;      // row (coalesced across lanes)
    float s[5] = {0.0f, 0.0f, 0.0f, 0.0f, 0.0f};
    for (int jb = g * (NSLOT / 4); jb < (g + 1) * (NSLOT / 4); ++jb) {
        const size_t base = (size_t)jb * N + i;
        #pragma unroll
        for (int p = 0; p < 5; ++p) s[p] += partials[p * PL + base];
    }
    #pragma unroll
    for (int p = 0; p < 5; ++p) sh[p][t] = s[p];
    __syncthreads();
    if (g == 0) {
        float v[5];
        #pragma unroll
        for (int p = 0; p < 5; ++p)
            v[p] = sh[p][lane] + sh[p][64 + lane] + sh[p][128 + lane] + sh[p][192 + lane];
        // loss_i = (UA - WB + V*log(Zo/Zt)) / Zt^3
        float li = (v[2] - v[4] + v[1] * __logf(v[3] / v[0])) / (v[0] * v[0] * v[0]);
        #pragma unroll
        for (int m = 32; m >= 1; m >>= 1) li += __shfl_xor(li, m);
        if (lane == 0)
            atomicAdd(out, li * (1.0f / ((float)N * (float)N)));   // WEIGHT=1
    }
}

extern "C" void kernel_launch(void* const* d_in, const int* in_sizes, int n_in,
                              void* d_out, int out_size, void* d_ws, size_t ws_size,
                              hipStream_t stream) {
    (void)in_sizes; (void)n_in; (void)out_size; (void)ws_size;
    const float* mo = (const float*)d_in[0];   // model_output [8192,512] fp32
    const float* tg = (const float*)d_in[1];   // targets      [8192,768] fp32
    float* out = (float*)d_out;

    char* ws = (char*)d_ws;
    unsigned short* Xt = (unsigned short*)ws;                          // 12.58 MB
    unsigned short* Xo = (unsigned short*)(ws + (size_t)N * DT * 2);   //  8.39 MB
    float* partials    = (float*)(ws + (size_t)N * DT * 2 + (size_t)N * DO * 2);
    // partials: 5 planes * 128 * 8192 * 4 B = 20.97 MB
    unsigned int* Wws  = (unsigned int*)((char*)partials + 5 * PL * sizeof(float));
    // Wws: 2080 tiles * 8192 u32 = 68.2 MB; total ws use ~110 MB

    norm_kernel<<<2 * (N / 4), 256, 0, stream>>>(tg, mo, Xt, Xo, out);  // also zeroes out
    fused_t_kernel<<<NTILE, 256, 0, stream>>>(Xt, partials, Wws);
    fused_o_kernel<<<NTILE, 256, 0, stream>>>(Xo, partials, Wws);
    reduce_kernel<<<N / 64, 256, 0, stream>>>(partials, out);
}

// Round 9
// 307.191 us; speedup vs baseline: 2.0256x; 1.0447x over previous
//
#include <hip/hip_runtime.h>

#define N    8192
#define DT   768
#define DO   512
#define BM   128
#define BN   128
#define TI   (N / BM)   // 64
#define TJ   (N / BN)   // 64
#define NTILE (TI * (TI + 1) / 2)   // 2080 upper-triangle tiles (2080 % 8 == 0)
#define NSLOT (2 * TJ)              // 128 partial slots per row
#define PL    ((size_t)NSLOT * N)   // one SoA plane: 128*8192 floats = 4 MB
#define NKT   (DT / 32)             // 24 teacher K-steps
#define NKO   (DO / 32)             // 16 student K-steps

typedef __attribute__((ext_vector_type(8))) short   short8;   // 8 bf16 = 4 VGPRs
typedef __attribute__((ext_vector_type(4))) float   floatx4;

struct alignas(8) us4 { unsigned short x[4]; };

// round-to-nearest-even fp32 -> bf16
__device__ inline unsigned short f2bf(float x) {
    union { float f; unsigned int u; } v; v.f = x;
    unsigned int r = v.u + 0x7fffu + ((v.u >> 16) & 1u);
    return (unsigned short)(r >> 16);
}
__device__ inline float bf2f(unsigned short u) {
    union { unsigned int u; float f; } v; v.u = ((unsigned int)u) << 16;
    return v.f;
}

// async global->LDS, 16B per lane (global_load_lds_dwordx4)
__device__ inline void gl2lds16(const unsigned short* g, unsigned short* l) {
    __builtin_amdgcn_global_load_lds(
        (const __attribute__((address_space(1))) unsigned int*)(const void*)g,
        (__attribute__((address_space(3))) unsigned int*)(void*)l,
        16, 0, 0);
}

// stage one 128x32 A-tile and B-tile (bf16) into an LDS ring slot.
// LDS destination LINEAR; bank-conflict swizzle via permuted GLOBAL source
// column chunk; matching XOR on the ds_read side. 4 VMEM instrs per thread.
template <int D>
__device__ inline void stage_tile(const unsigned short* __restrict__ X,
                                  unsigned short* sAb, unsigned short* sBb,
                                  int i0, int j0, int k, int t) {
    #pragma unroll
    for (int h = 0; h < 2; ++h) {
        const int idx = t + h * 256;        // 0..511; lane-contiguous per wave
        const int r   = idx >> 2;
        const int cs  = ((idx & 3) ^ ((r >> 1) & 3)) << 3;   // swizzled col-chunk
        gl2lds16(X + (size_t)(i0 + r) * D + k + cs, &sAb[idx * 8]);
        gl2lds16(X + (size_t)(j0 + r) * D + k + cs, &sBb[idx * 8]);
    }
}

// R9: interleaved fragment-read / MFMA order — bf[0..3] up front, then per-mi
// {1 ds_read_b128, 4 MFMA}. Shallower lgkm chain; DS and MFMA mixed in program
// order so waves drifted by the K-rotation overlap pipes instead of bursting.
__device__ inline void mfma_step(const unsigned short* __restrict__ sAb,
                                 const unsigned short* __restrict__ sBb,
                                 floatx4 (&acc)[4][4],
                                 int wm, int wn, int lr, int lgx) {
    short8 bf[4];
    #pragma unroll
    for (int ni = 0; ni < 4; ++ni)
        bf[ni] = *(const short8*)&sBb[(wn * 64 + ni * 16 + lr) * 32 + (lgx << 3)];
    #pragma unroll
    for (int mi = 0; mi < 4; ++mi) {
        const short8 af = *(const short8*)&sAb[(wm * 64 + mi * 16 + lr) * 32 + (lgx << 3)];
        #pragma unroll
        for (int ni = 0; ni < 4; ++ni)
            acc[mi][ni] = __builtin_amdgcn_mfma_f32_16x16x32_bf16(
                af, bf[ni], acc[mi][ni], 0, 0, 0);
    }
}

// bid -> (ti, tj): chunked XCD swizzle + SUPER-BLOCK enumeration (R8, proven:
// FETCH 190->129 MB). 8x8 super-blocks; diagonal SBs 36 tiles, off-diag 64.
__device__ inline void tile_coords(int bid, int& ti, int& tj) {
    int swb = (bid & 7) * (NTILE / 8) + (bid >> 3);   // contiguous per XCD
    int sti = 0, stj = 0;
    for (;;) {
        const int sz = (sti == stj) ? 36 : 64;
        if (swb < sz) break;
        swb -= sz;
        if (++stj == 8) { ++sti; stj = sti; }
    }
    int i, j;
    if (sti == stj) {            // triangular SB: row i has 8-i tiles (j >= i)
        i = 0;
        while (swb >= 8 - i) { swb -= 8 - i; ++i; }
        j = i + swb;
    } else {                     // full SB: row-major 8x8
        i = swb >> 3;
        j = swb & 7;
    }
    ti = sti * 8 + i;
    tj = stj * 8 + j;
}

// ---------------- row-normalize fp32 -> bf16 (one wave per row) ----------------
__global__ void norm_kernel(const float* __restrict__ Tg,
                            const float* __restrict__ Mo,
                            unsigned short* __restrict__ Xt,
                            unsigned short* __restrict__ Xo,
                            float* __restrict__ zero_me) {
    if (blockIdx.x == 0 && threadIdx.x == 0) zero_me[0] = 0.0f;
    int bid = blockIdx.x;
    const float* X; unsigned short* Xn; int D;
    if (bid < N / 4) { X = Tg; Xn = Xt; D = DT; }
    else             { bid -= N / 4; X = Mo; Xn = Xo; D = DO; }
    const int row  = bid * 4 + (threadIdx.x >> 6);
    const int lane = threadIdx.x & 63;
    const int nch  = D >> 8;                       // 3 (DT) or 2 (DO)
    const float* xr = X + (size_t)row * D;
    floatx4 vc[3];
    float ss = 0.0f;
    #pragma unroll
    for (int h = 0; h < 3; ++h) {
        if (h < nch) {
            vc[h] = *(const floatx4*)(xr + lane * 4 + h * 256);
            ss += vc[h][0] * vc[h][0] + vc[h][1] * vc[h][1]
                + vc[h][2] * vc[h][2] + vc[h][3] * vc[h][3];
        }
    }
    #pragma unroll
    for (int m = 32; m >= 1; m >>= 1) ss += __shfl_xor(ss, m);
    const float scale = 1.0f / fmaxf(sqrtf(ss), 1e-8f);
    unsigned short* outr = Xn + (size_t)row * D;
    #pragma unroll
    for (int h = 0; h < 3; ++h) {
        if (h < nch) {
            us4 o;
            #pragma unroll
            for (int j = 0; j < 4; ++j) o.x[j] = f2bf(vc[h][j] * scale);
            *(us4*)(outr + lane * 4 + h * 256) = o;
        }
    }
}

// ---------------- teacher kernel: GEMM + Zt/V/UA stats + W -> global ----------
// R9 K-loop: R8 skeleton (ring-3, lookahead-2, ONE barrier/step, counted
// vmcnt(4)) + convoy-breakers:
//  * per-block K-START ROTATION: block starts at step offset (bid%3)*NKT/3;
//    k = ((s+off)%NKT)*32. Accumulation is commutative; ring slot = s%3.
//    Co-resident blocks' staging bursts land in each other's MFMA phases.
//  * setprio(1) around the compute cluster (pays once waves are de-phased).
__launch_bounds__(256, 3)
__global__ void fused_t_kernel(const unsigned short* __restrict__ Xt,
                               float* __restrict__ partials,
                               unsigned int* __restrict__ Wws) {
    __shared__ unsigned short sA[3][BM * 32];     // 3 x 8 KB
    __shared__ unsigned short sB[3][BN * 32];     // 3 x 8 KB   (total 48 KB)

    const int t    = threadIdx.x;
    const int lane = t & 63;
    const int w    = t >> 6;
    const int wm   = w >> 1, wn = w & 1;
    const int lr   = lane & 15, lg = lane >> 4;
    const int lgx  = lg ^ ((lr >> 1) & 3);

    int ti, tj; tile_coords(blockIdx.x, ti, tj);
    const bool offdiag = (ti != tj);
    const int i0 = ti * BM, j0 = tj * BN;
    const int off = (blockIdx.x % 3) * (NKT / 3);           // 0, 8, 16
    unsigned int* const wt = Wws + (size_t)blockIdx.x * 8192;

    floatx4 acc[4][4];
    #pragma unroll
    for (int a = 0; a < 4; ++a)
        #pragma unroll
        for (int b = 0; b < 4; ++b)
            acc[a][b] = (floatx4){0.0f, 0.0f, 0.0f, 0.0f};

    {
        const int k0 = (off % NKT) * 32, k1 = ((1 + off) % NKT) * 32;
        stage_tile<DT>(Xt, sA[0], sB[0], i0, j0, k0, t);
        stage_tile<DT>(Xt, sA[1], sB[1], i0, j0, k1, t);
    }

    for (int s = 0; s < NKT; ++s) {
        if (s + 1 < NKT) asm volatile("s_waitcnt vmcnt(4)" ::: "memory");
        else             asm volatile("s_waitcnt vmcnt(0)" ::: "memory");
        __builtin_amdgcn_s_barrier();
        asm volatile("" ::: "memory");
        if (s + 2 < NKT)
            stage_tile<DT>(Xt, sA[(s + 2) % 3], sB[(s + 2) % 3], i0, j0,
                           ((s + 2 + off) % NKT) * 32, t);
        __builtin_amdgcn_s_setprio(1);
        mfma_step(sA[s % 3], sB[s % 3], acc, wm, wn, lr, lgx);
        __builtin_amdgcn_s_setprio(0);
        asm volatile("" ::: "memory");
    }

    // ---- epilogue: Zt, V, Sum(e3*a) per row (both orientations); W packed ----
    // C/D layout: col = lane&15, row = (lane>>4)*4 + reg
    {
        float czt[4], cvv[4], cua[4];
        #pragma unroll
        for (int ni = 0; ni < 4; ++ni) { czt[ni] = 0.0f; cvv[ni] = 0.0f; cua[ni] = 0.0f; }
        #pragma unroll
        for (int mi = 0; mi < 4; ++mi) {
            unsigned int wpk[4][2];                        // [ni][r>>1] bf16 pairs
            #pragma unroll
            for (int r = 0; r < 4; ++r) {
                const int row = wm * 64 + mi * 16 + lg * 4 + r;
                const int gi  = i0 + row;
                float zt = 0.0f, vv = 0.0f, ua = 0.0f;
                #pragma unroll
                for (int ni = 0; ni < 4; ++ni) {
                    const int gj = j0 + wn * 64 + ni * 16 + lr;
                    const float a = acc[mi][ni][r];
                    float ea = __expf(a - 1.0f);
                    if (gi == gj) ea = 0.0f;               // diagonal -> prob 0
                    const float e3 = ea * ea * ea;
                    zt += ea; vv += e3; ua += e3 * a;
                    czt[ni] += ea; cvv[ni] += e3; cua[ni] += e3 * a;
                    if ((r & 1) == 0) wpk[ni][r >> 1]  = (unsigned int)f2bf(e3);
                    else              wpk[ni][r >> 1] |= ((unsigned int)f2bf(e3)) << 16;
                }
                #pragma unroll
                for (int m = 8; m >= 1; m >>= 1) {
                    zt += __shfl_xor(zt, m);
                    vv += __shfl_xor(vv, m);
                    ua += __shfl_xor(ua, m);
                }
                if (lr == 0) {
                    const size_t base = (size_t)(tj * 2 + wn) * N + gi;
                    partials[0 * PL + base] = zt;
                    partials[1 * PL + base] = vv;
                    partials[2 * PL + base] = ua;
                }
            }
            #pragma unroll
            for (int ni = 0; ni < 4; ++ni)
                #pragma unroll
                for (int rp = 0; rp < 2; ++rp)
                    wt[(mi * 8 + ni * 2 + rp) * 256 + t] = wpk[ni][rp];   // coalesced
        }
        if (offdiag) {
            #pragma unroll
            for (int ni = 0; ni < 4; ++ni) {
                #pragma unroll
                for (int m = 16; m <= 32; m <<= 1) {
                    czt[ni] += __shfl_xor(czt[ni], m);
                    cvv[ni] += __shfl_xor(cvv[ni], m);
                    cua[ni] += __shfl_xor(cua[ni], m);
                }
            }
            if (lg == 0) {
                #pragma unroll
                for (int ni = 0; ni < 4; ++ni) {
                    const int gj = j0 + wn * 64 + ni * 16 + lr;   // contiguous in lr
                    const size_t base = (size_t)(ti * 2 + wm) * N + gj;
                    partials[0 * PL + base] = czt[ni];
                    partials[1 * PL + base] = cvv[ni];
                    partials[2 * PL + base] = cua[ni];
                }
            }
        }
    }
}

// ---------------- student kernel: GEMM + Zo/WB stats (W from global) ---------
__launch_bounds__(256, 3)
__global__ void fused_o_kernel(const unsigned short* __restrict__ Xo,
                               float* __restrict__ partials,
                               const unsigned int* __restrict__ Wws) {
    __shared__ unsigned short sA[3][BM * 32];
    __shared__ unsigned short sB[3][BN * 32];

    const int t    = threadIdx.x;
    const int lane = t & 63;
    const int w    = t >> 6;
    const int wm   = w >> 1, wn = w & 1;
    const int lr   = lane & 15, lg = lane >> 4;
    const int lgx  = lg ^ ((lr >> 1) & 3);

    int ti, tj; tile_coords(blockIdx.x, ti, tj);
    const bool offdiag = (ti != tj);
    const int i0 = ti * BM, j0 = tj * BN;
    const int off = (blockIdx.x % 3) * 5;                   // 0, 5, 10 (NKO=16)
    const unsigned int* const wt = Wws + (size_t)blockIdx.x * 8192;

    floatx4 acc[4][4];
    #pragma unroll
    for (int a = 0; a < 4; ++a)
        #pragma unroll
        for (int b = 0; b < 4; ++b)
            acc[a][b] = (floatx4){0.0f, 0.0f, 0.0f, 0.0f};

    {
        const int k0 = (off % NKO) * 32, k1 = ((1 + off) % NKO) * 32;
        stage_tile<DO>(Xo, sA[0], sB[0], i0, j0, k0, t);
        stage_tile<DO>(Xo, sA[1], sB[1], i0, j0, k1, t);
    }

    for (int s = 0; s < NKO; ++s) {
        if (s + 1 < NKO) asm volatile("s_waitcnt vmcnt(4)" ::: "memory");
        else             asm volatile("s_waitcnt vmcnt(0)" ::: "memory");
        __builtin_amdgcn_s_barrier();
        asm volatile("" ::: "memory");
        if (s + 2 < NKO)
            stage_tile<DO>(Xo, sA[(s + 2) % 3], sB[(s + 2) % 3], i0, j0,
                           ((s + 2 + off) % NKO) * 32, t);
        __builtin_amdgcn_s_setprio(1);
        mfma_step(sA[s % 3], sB[s % 3], acc, wm, wn, lr, lgx);
        __builtin_amdgcn_s_setprio(0);
        asm volatile("" ::: "memory");
    }

    // ---- epilogue: Zo, Sum(W*b) per row (both orientations). ----
    {
        unsigned int wld[32];
        #pragma unroll
        for (int pi = 0; pi < 32; ++pi)
            wld[pi] = wt[pi * 256 + t];        // coalesced; same-XCD L2 mostly
        float czo[4], cwb[4];
        #pragma unroll
        for (int ni = 0; ni < 4; ++ni) { czo[ni] = 0.0f; cwb[ni] = 0.0f; }
        #pragma unroll
        for (int mi = 0; mi < 4; ++mi) {
            #pragma unroll
            for (int r = 0; r < 4; ++r) {
                const int row = wm * 64 + mi * 16 + lg * 4 + r;
                const int gi  = i0 + row;
                float zo = 0.0f, wb = 0.0f;
                #pragma unroll
                for (int ni = 0; ni < 4; ++ni) {
                    const int gj = j0 + wn * 64 + ni * 16 + lr;
                    const float b = acc[mi][ni][r];
                    float eb = __expf(b - 1.0f);
                    if (gi == gj) eb = 0.0f;
                    const unsigned int pw = wld[mi * 8 + ni * 2 + (r >> 1)];
                    const float wgt = bf2f((unsigned short)((r & 1) ? (pw >> 16)
                                                                    : (pw & 0xffffu)));
                    zo += eb; wb += wgt * b;   // diag: W==0 -> no contribution
                    czo[ni] += eb; cwb[ni] += wgt * b;
                }
                #pragma unroll
                for (int m = 8; m >= 1; m >>= 1) {
                    zo += __shfl_xor(zo, m);
                    wb += __shfl_xor(wb, m);
                }
                if (lr == 0) {
                    const size_t base = (size_t)(tj * 2 + wn) * N + gi;
                    partials[3 * PL + base] = zo;
                    partials[4 * PL + base] = wb;
                }
            }
        }
        if (offdiag) {
            #pragma unroll
            for (int ni = 0; ni < 4; ++ni) {
                #pragma unroll
                for (int m = 16; m <= 32; m <<= 1) {
                    czo[ni] += __shfl_xor(czo[ni], m);
                    cwb[ni] += __shfl_xor(cwb[ni], m);
                }
            }
            if (lg == 0) {
                #pragma unroll
                for (int ni = 0; ni < 4; ++ni) {
                    const int gj = j0 + wn * 64 + ni * 16 + lr;
                    const size_t base = (size_t)(ti * 2 + wm) * N + gj;
                    partials[3 * PL + base] = czo[ni];
                    partials[4 * PL + base] = cwb[ni];
                }
            }
        }
    }
}

// ---------------- final per-row combine + scalar reduce ----------------
__global__ void reduce_kernel(const float* __restrict__ partials,
                              float* __restrict__ out) {
    __shared__ float sh[5][256];
    const int t    = threadIdx.x;
    const int lane = t & 63;
    const int g    = t >> 6;
    const int i    = blockIdx.x * 64 + lane;      // row (coalesced across lanes)
    float s[5] = {0.0f, 0.0f, 0.0f, 0.0f, 0.0f};
    for (int jb = g * (NSLOT / 4); jb < (g + 1) * (NSLOT / 4); ++jb) {
        const size_t base = (size_t)jb * N + i;
        #pragma unroll
        for (int p = 0; p < 5; ++p) s[p] += partials[p * PL + base];
    }
    #pragma unroll
    for (int p = 0; p < 5; ++p) sh[p][t] = s[p];
    __syncthreads();
    if (g == 0) {
        float v[5];
        #pragma unroll
        for (int p = 0; p < 5; ++p)
            v[p] = sh[p][lane] + sh[p][64 + lane] + sh[p][128 + lane] + sh[p][192 + lane];
        // loss_i = (UA - WB + V*log(Zo/Zt)) / Zt^3
        float li = (v[2] - v[4] + v[1] * __logf(v[3] / v[0])) / (v[0] * v[0] * v[0]);
        #pragma unroll
        for (int m = 32; m >= 1; m >>= 1) li += __shfl_xor(li, m);
        if (lane == 0)
            atomicAdd(out, li * (1.0f / ((float)N * (float)N)));   // WEIGHT=1
    }
}

extern "C" void kernel_launch(void* const* d_in, const int* in_sizes, int n_in,
                              void* d_out, int out_size, void* d_ws, size_t ws_size,
                              hipStream_t stream) {
    (void)in_sizes; (void)n_in; (void)out_size; (void)ws_size;
    const float* mo = (const float*)d_in[0];   // model_output [8192,512] fp32
    const float* tg = (const float*)d_in[1];   // targets      [8192,768] fp32
    float* out = (float*)d_out;

    char* ws = (char*)d_ws;
    unsigned short* Xt = (unsigned short*)ws;                          // 12.58 MB
    unsigned short* Xo = (unsigned short*)(ws + (size_t)N * DT * 2);   //  8.39 MB
    float* partials    = (float*)(ws + (size_t)N * DT * 2 + (size_t)N * DO * 2);
    // partials: 5 planes * 128 * 8192 * 4 B = 20.97 MB
    unsigned int* Wws  = (unsigned int*)((char*)partials + 5 * PL * sizeof(float));
    // Wws: 2080 tiles * 8192 u32 = 68.2 MB; total ws use ~110 MB

    norm_kernel<<<2 * (N / 4), 256, 0, stream>>>(tg, mo, Xt, Xo, out);  // also zeroes out
    fused_t_kernel<<<NTILE, 256, 0, stream>>>(Xt, partials, Wws);
    fused_o_kernel<<<NTILE, 256, 0, stream>>>(Xo, partials, Wws);
    reduce_kernel<<<N / 64, 256, 0, stream>>>(partials, out);
}

// Round 10
// 293.860 us; speedup vs baseline: 2.1175x; 1.0454x over previous
//
#include <hip/hip_runtime.h>

#define N    8192
#define DT   768
#define DO   512
#define BM   128
#define BN   128
#define TI   (N / BM)   // 64
#define TJ   (N / BN)   // 64
#define NTILE (TI * (TI + 1) / 2)   // 2080 upper-triangle tiles (2080 % 8 == 0)
#define NSLOT (2 * TJ)              // 128 partial slots per row
#define PL    ((size_t)NSLOT * N)   // one SoA plane: 128*8192 floats = 4 MB

typedef __attribute__((ext_vector_type(8))) short   short8;   // 8 bf16 = 4 VGPRs
typedef __attribute__((ext_vector_type(4))) float   floatx4;

struct alignas(8) us4 { unsigned short x[4]; };

// round-to-nearest-even fp32 -> bf16
__device__ inline unsigned short f2bf(float x) {
    union { float f; unsigned int u; } v; v.f = x;
    unsigned int r = v.u + 0x7fffu + ((v.u >> 16) & 1u);
    return (unsigned short)(r >> 16);
}
__device__ inline float bf2f(unsigned short u) {
    union { unsigned int u; float f; } v; v.u = ((unsigned int)u) << 16;
    return v.f;
}

// async global->LDS, 16B per lane (global_load_lds_dwordx4)
__device__ inline void gl2lds16(const unsigned short* g, unsigned short* l) {
    __builtin_amdgcn_global_load_lds(
        (const __attribute__((address_space(1))) unsigned int*)(const void*)g,
        (__attribute__((address_space(3))) unsigned int*)(void*)l,
        16, 0, 0);
}

// stage one 128x32 A-tile and B-tile (bf16) into LDS via global_load_lds.
// LDS destination LINEAR (global_load_lds writes base+lane*16); bank-conflict
// swizzle applied by permuting the GLOBAL source column chunk; matching XOR
// on the ds_read side (2-way residual = free). 4 VMEM instrs per thread.
template <int D>
__device__ inline void stage_tile(const unsigned short* __restrict__ X,
                                  unsigned short* sA, unsigned short* sB,
                                  int i0, int j0, int k, int t) {
    #pragma unroll
    for (int h = 0; h < 2; ++h) {
        const int idx = t + h * 256;        // 0..511; lane-contiguous per wave
        const int r   = idx >> 2;
        const int cs  = ((idx & 3) ^ ((r >> 1) & 3)) << 3;   // swizzled col-chunk
        gl2lds16(X + (size_t)(i0 + r) * D + k + cs, &sA[idx * 8]);
        gl2lds16(X + (size_t)(j0 + r) * D + k + cs, &sB[idx * 8]);
    }
}

// bid -> (ti, tj): chunked XCD swizzle + SUPER-BLOCK enumeration (R8, proven:
// FETCH 190->129 MB on the split kernel). The 64x64 tile triangle is cut into
// 8x8 super-blocks; diagonal SBs hold 36 tiles, off-diagonal 64
// (8*36 + 28*64 = 2080). SBs enumerated (sti, stj>=sti) row-major, tiles
// row-major within. Each XCD's contiguous 260-rank chunk spans ~4 SBs, so its
// in-flight blocks touch ~16 panels (~3 MB) -> A and B both L2-resident.
__device__ inline void tile_coords(int bid, int& ti, int& tj) {
    int swb = (bid & 7) * (NTILE / 8) + (bid >> 3);   // contiguous per XCD
    int sti = 0, stj = 0;
    for (;;) {
        const int sz = (sti == stj) ? 36 : 64;
        if (swb < sz) break;
        swb -= sz;
        if (++stj == 8) { ++sti; stj = sti; }
    }
    int i, j;
    if (sti == stj) {            // triangular SB: row i has 8-i tiles (j >= i)
        i = 0;
        while (swb >= 8 - i) { swb -= 8 - i; ++i; }
        j = i + swb;
    } else {                     // full SB: row-major 8x8
        i = swb >> 3;
        j = swb & 7;
    }
    ti = sti * 8 + i;
    tj = stj * 8 + j;
}

// ---------------- row-normalize fp32 -> bf16 (one wave per row) ----------------
// Single launch covers both matrices; loads cached in registers (single pass).
__global__ void norm_kernel(const float* __restrict__ Tg,
                            const float* __restrict__ Mo,
                            unsigned short* __restrict__ Xt,
                            unsigned short* __restrict__ Xo,
                            float* __restrict__ zero_me) {
    if (blockIdx.x == 0 && threadIdx.x == 0) zero_me[0] = 0.0f;
    int bid = blockIdx.x;
    const float* X; unsigned short* Xn; int D;
    if (bid < N / 4) { X = Tg; Xn = Xt; D = DT; }
    else             { bid -= N / 4; X = Mo; Xn = Xo; D = DO; }
    const int row  = bid * 4 + (threadIdx.x >> 6);
    const int lane = threadIdx.x & 63;
    const int nch  = D >> 8;                       // 3 (DT) or 2 (DO)
    const float* xr = X + (size_t)row * D;
    floatx4 vc[3];
    float ss = 0.0f;
    #pragma unroll
    for (int h = 0; h < 3; ++h) {
        if (h < nch) {
            vc[h] = *(const floatx4*)(xr + lane * 4 + h * 256);
            ss += vc[h][0] * vc[h][0] + vc[h][1] * vc[h][1]
                + vc[h][2] * vc[h][2] + vc[h][3] * vc[h][3];
        }
    }
    #pragma unroll
    for (int m = 32; m >= 1; m >>= 1) ss += __shfl_xor(ss, m);
    const float scale = 1.0f / fmaxf(sqrtf(ss), 1e-8f);
    unsigned short* outr = Xn + (size_t)row * D;
    #pragma unroll
    for (int h = 0; h < 3; ++h) {
        if (h < nch) {
            us4 o;
            #pragma unroll
            for (int j = 0; j < 4; ++j) o.x[j] = f2bf(vc[h][j] * scale);
            *(us4*)(outr + lane * 4 + h * 256) = o;
        }
    }
}

// ---------------- fused dual-GEMM + softmax-stat tile kernel (R2 structure) ----
// Symmetric-tile scheme (ti <= tj): row-sums (lr-reduce) -> slot tj*2+wn;
// col-sums (lg-reduce) -> slot ti*2+wm. Per row, slots 0..127 written once.
// W = e3 parked bf16 in LDS sW[idx][t] (per-thread private, conflict-free)
// between the two GEMMs -- no global W traffic, no register-pressure cost.
// 48 KB LDS -> 3 blocks/CU, 84 VGPR. 2-barrier full-drain K-step cadence
// (measured equal to every pipelined variant at this tile shape, R2..R9).
// partials layout (SoA, full-line stores): 5 planes [NSLOT][N] f32
//   plane 0..4 = Zt, V, UA, Zo, WB.
__launch_bounds__(256, 3)
__global__ void fused_kernel(const unsigned short* __restrict__ Xt,
                             const unsigned short* __restrict__ Xo,
                             float* __restrict__ partials) {
    __shared__ unsigned short sA[BM * 32];     // 8 KB
    __shared__ unsigned short sB[BN * 32];     // 8 KB
    __shared__ unsigned short sW[64 * 256];    // 32 KB: [idx 0..63][thread 0..255]

    const int t    = threadIdx.x;
    const int lane = t & 63;
    const int w    = t >> 6;
    const int wm   = w >> 1, wn = w & 1;
    const int lr   = lane & 15, lg = lane >> 4;
    const int lgx  = lg ^ ((lr >> 1) & 3);     // swizzled read chunk index

    int ti, tj; tile_coords(blockIdx.x, ti, tj);
    const bool offdiag = (ti != tj);
    const int i0 = ti * BM, j0 = tj * BN;

    floatx4 acc[4][4];
    #pragma unroll
    for (int a = 0; a < 4; ++a)
        #pragma unroll
        for (int b = 0; b < 4; ++b)
            acc[a][b] = (floatx4){0.0f, 0.0f, 0.0f, 0.0f};

    // ---- teacher GEMM: S_t tile, K = DT ----
    for (int k = 0; k < DT; k += 32) {
        stage_tile<DT>(Xt, sA, sB, i0, j0, k, t);
        asm volatile("s_waitcnt vmcnt(0)" ::: "memory");
        __syncthreads();
        short8 af[4], bf[4];
        #pragma unroll
        for (int mi = 0; mi < 4; ++mi)
            af[mi] = *(const short8*)&sA[(wm * 64 + mi * 16 + lr) * 32 + (lgx << 3)];
        #pragma unroll
        for (int ni = 0; ni < 4; ++ni)
            bf[ni] = *(const short8*)&sB[(wn * 64 + ni * 16 + lr) * 32 + (lgx << 3)];
        #pragma unroll
        for (int mi = 0; mi < 4; ++mi)
            #pragma unroll
            for (int ni = 0; ni < 4; ++ni)
                acc[mi][ni] = __builtin_amdgcn_mfma_f32_16x16x32_bf16(
                    af[mi], bf[ni], acc[mi][ni], 0, 0, 0);
        __syncthreads();
    }

    // ---- teacher epilogue: Zt, V, Sum(e3*a) per row (both orientations);
    //      park W=e3 (bf16) in LDS. C/D layout: col=lane&15, row=(lane>>4)*4+reg
    {
        float czt[4], cvv[4], cua[4];
        #pragma unroll
        for (int ni = 0; ni < 4; ++ni) { czt[ni] = 0.0f; cvv[ni] = 0.0f; cua[ni] = 0.0f; }
        #pragma unroll
        for (int mi = 0; mi < 4; ++mi) {
            #pragma unroll
            for (int r = 0; r < 4; ++r) {
                const int row = wm * 64 + mi * 16 + lg * 4 + r;
                const int gi  = i0 + row;
                float zt = 0.0f, vv = 0.0f, ua = 0.0f;
                #pragma unroll
                for (int ni = 0; ni < 4; ++ni) {
                    const int gj = j0 + wn * 64 + ni * 16 + lr;
                    const float a = acc[mi][ni][r];
                    float ea = __expf(a - 1.0f);
                    if (gi == gj) ea = 0.0f;               // diagonal -> prob 0
                    const float e3 = ea * ea * ea;
                    zt += ea; vv += e3; ua += e3 * a;
                    czt[ni] += ea; cvv[ni] += e3; cua[ni] += e3 * a;
                    sW[(mi * 16 + ni * 4 + r) * 256 + t] = f2bf(e3);
                }
                #pragma unroll
                for (int m = 8; m >= 1; m >>= 1) {
                    zt += __shfl_xor(zt, m);
                    vv += __shfl_xor(vv, m);
                    ua += __shfl_xor(ua, m);
                }
                if (lr == 0) {
                    const size_t base = (size_t)(tj * 2 + wn) * N + gi;
                    partials[0 * PL + base] = zt;
                    partials[1 * PL + base] = vv;
                    partials[2 * PL + base] = ua;
                }
            }
        }
        if (offdiag) {
            #pragma unroll
            for (int ni = 0; ni < 4; ++ni) {
                #pragma unroll
                for (int m = 16; m <= 32; m <<= 1) {
                    czt[ni] += __shfl_xor(czt[ni], m);
                    cvv[ni] += __shfl_xor(cvv[ni], m);
                    cua[ni] += __shfl_xor(cua[ni], m);
                }
            }
            if (lg == 0) {
                #pragma unroll
                for (int ni = 0; ni < 4; ++ni) {
                    const int gj = j0 + wn * 64 + ni * 16 + lr;   // contiguous in lr
                    const size_t base = (size_t)(ti * 2 + wm) * N + gj;
                    partials[0 * PL + base] = czt[ni];
                    partials[1 * PL + base] = cvv[ni];
                    partials[2 * PL + base] = cua[ni];
                }
            }
        }
    }
    // No barrier needed: sW is per-thread private; sA/sB free to restage
    // (all reads of the last teacher tile completed before the final barrier).

    // ---- student GEMM: S_o tile, K = DO (same accumulator registers) ----
    #pragma unroll
    for (int a = 0; a < 4; ++a)
        #pragma unroll
        for (int b = 0; b < 4; ++b)
            acc[a][b] = (floatx4){0.0f, 0.0f, 0.0f, 0.0f};

    for (int k = 0; k < DO; k += 32) {
        stage_tile<DO>(Xo, sA, sB, i0, j0, k, t);
        asm volatile("s_waitcnt vmcnt(0)" ::: "memory");
        __syncthreads();
        short8 af[4], bf[4];
        #pragma unroll
        for (int mi = 0; mi < 4; ++mi)
            af[mi] = *(const short8*)&sA[(wm * 64 + mi * 16 + lr) * 32 + (lgx << 3)];
        #pragma unroll
        for (int ni = 0; ni < 4; ++ni)
            bf[ni] = *(const short8*)&sB[(wn * 64 + ni * 16 + lr) * 32 + (lgx << 3)];
        #pragma unroll
        for (int mi = 0; mi < 4; ++mi)
            #pragma unroll
            for (int ni = 0; ni < 4; ++ni)
                acc[mi][ni] = __builtin_amdgcn_mfma_f32_16x16x32_bf16(
                    af[mi], bf[ni], acc[mi][ni], 0, 0, 0);
        __syncthreads();
    }

    // ---- final epilogue: Zo, Sum(W*b) per row (both orientations) ----
    {
        float czo[4], cwb[4];
        #pragma unroll
        for (int ni = 0; ni < 4; ++ni) { czo[ni] = 0.0f; cwb[ni] = 0.0f; }
        #pragma unroll
        for (int mi = 0; mi < 4; ++mi) {
            #pragma unroll
            for (int r = 0; r < 4; ++r) {
                const int row = wm * 64 + mi * 16 + lg * 4 + r;
                const int gi  = i0 + row;
                float zo = 0.0f, wb = 0.0f;
                #pragma unroll
                for (int ni = 0; ni < 4; ++ni) {
                    const int gj = j0 + wn * 64 + ni * 16 + lr;
                    const float b = acc[mi][ni][r];
                    float eb = __expf(b - 1.0f);
                    if (gi == gj) eb = 0.0f;
                    const float wgt = bf2f(sW[(mi * 16 + ni * 4 + r) * 256 + t]);
                    zo += eb; wb += wgt * b;   // diag: W==0 -> no contribution
                    czo[ni] += eb; cwb[ni] += wgt * b;
                }
                #pragma unroll
                for (int m = 8; m >= 1; m >>= 1) {
                    zo += __shfl_xor(zo, m);
                    wb += __shfl_xor(wb, m);
                }
                if (lr == 0) {
                    const size_t base = (size_t)(tj * 2 + wn) * N + gi;
                    partials[3 * PL + base] = zo;
                    partials[4 * PL + base] = wb;
                }
            }
        }
        if (offdiag) {
            #pragma unroll
            for (int ni = 0; ni < 4; ++ni) {
                #pragma unroll
                for (int m = 16; m <= 32; m <<= 1) {
                    czo[ni] += __shfl_xor(czo[ni], m);
                    cwb[ni] += __shfl_xor(cwb[ni], m);
                }
            }
            if (lg == 0) {
                #pragma unroll
                for (int ni = 0; ni < 4; ++ni) {
                    const int gj = j0 + wn * 64 + ni * 16 + lr;   // contiguous in lr
                    const size_t base = (size_t)(ti * 2 + wm) * N + gj;
                    partials[3 * PL + base] = czo[ni];
                    partials[4 * PL + base] = cwb[ni];
                }
            }
        }
    }
}

// ---------------- final per-row combine + scalar reduce ----------------
// 128 blocks; each block: 64 rows, 4 waves split the 128 slots (32 each),
// LDS combine, wave 0 computes per-row loss + block partial -> one atomic.
__global__ void reduce_kernel(const float* __restrict__ partials,
                              float* __restrict__ out) {
    __shared__ float sh[5][256];
    const int t    = threadIdx.x;
    const int lane = t & 63;
    const int g    = t >> 6;
    const int i    = blockIdx.x * 64 + lane;      // row (coalesced across lanes)
    float s[5] = {0.0f, 0.0f, 0.0f, 0.0f, 0.0f};
    for (int jb = g * (NSLOT / 4); jb < (g + 1) * (NSLOT / 4); ++jb) {
        const size_t base = (size_t)jb * N + i;
        #pragma unroll
        for (int p = 0; p < 5; ++p) s[p] += partials[p * PL + base];
    }
    #pragma unroll
    for (int p = 0; p < 5; ++p) sh[p][t] = s[p];
    __syncthreads();
    if (g == 0) {
        float v[5];
        #pragma unroll
        for (int p = 0; p < 5; ++p)
            v[p] = sh[p][lane] + sh[p][64 + lane] + sh[p][128 + lane] + sh[p][192 + lane];
        // loss_i = (UA - WB + V*log(Zo/Zt)) / Zt^3
        float li = (v[2] - v[4] + v[1] * __logf(v[3] / v[0])) / (v[0] * v[0] * v[0]);
        #pragma unroll
        for (int m = 32; m >= 1; m >>= 1) li += __shfl_xor(li, m);
        if (lane == 0)
            atomicAdd(out, li * (1.0f / ((float)N * (float)N)));   // WEIGHT=1
    }
}

extern "C" void kernel_launch(void* const* d_in, const int* in_sizes, int n_in,
                              void* d_out, int out_size, void* d_ws, size_t ws_size,
                              hipStream_t stream) {
    (void)in_sizes; (void)n_in; (void)out_size; (void)ws_size;
    const float* mo = (const float*)d_in[0];   // model_output [8192,512] fp32
    const float* tg = (const float*)d_in[1];   // targets      [8192,768] fp32
    float* out = (float*)d_out;

    char* ws = (char*)d_ws;
    unsigned short* Xt = (unsigned short*)ws;                          // 12.58 MB
    unsigned short* Xo = (unsigned short*)(ws + (size_t)N * DT * 2);   //  8.39 MB
    float* partials    = (float*)(ws + (size_t)N * DT * 2 + (size_t)N * DO * 2);
    // partials: 5 planes * 128 * 8192 * 4 B = 20.97 MB; total ws use ~41.9 MB

    norm_kernel<<<2 * (N / 4), 256, 0, stream>>>(tg, mo, Xt, Xo, out);  // also zeroes out
    fused_kernel<<<NTILE, 256, 0, stream>>>(Xt, Xo, partials);
    reduce_kernel<<<N / 64, 256, 0, stream>>>(partials, out);
}

// Round 11
// 283.905 us; speedup vs baseline: 2.1918x; 1.0351x over previous
//
#include <hip/hip_runtime.h>

#define N    8192
#define DT   768
#define DO   512
#define BM   128
#define BN   128
#define TI   (N / BM)   // 64
#define TJ   (N / BN)   // 64
#define NTILE (TI * (TI + 1) / 2)   // 2080 upper-triangle tiles (2080 % 8 == 0)
#define NSLOT (2 * TJ)              // 128 partial slots per row
#define PL    ((size_t)NSLOT * N)   // one SoA plane: 128*8192 floats = 4 MB
#define NKT   (DT / 32)             // 24 teacher K-chunks
#define NKO   (DO / 32)             // 16 student K-chunks

typedef __attribute__((ext_vector_type(8))) short   short8;   // 8 bf16 = 4 VGPRs
typedef __attribute__((ext_vector_type(4))) float   floatx4;

struct alignas(8) us4 { unsigned short x[4]; };

// round-to-nearest-even fp32 -> bf16
__device__ inline unsigned short f2bf(float x) {
    union { float f; unsigned int u; } v; v.f = x;
    unsigned int r = v.u + 0x7fffu + ((v.u >> 16) & 1u);
    return (unsigned short)(r >> 16);
}
__device__ inline float bf2f(unsigned short u) {
    union { unsigned int u; float f; } v; v.u = ((unsigned int)u) << 16;
    return v.f;
}

// async global->LDS, 16B per lane (global_load_lds_dwordx4)
__device__ inline void gl2lds16(const unsigned short* g, unsigned short* l) {
    __builtin_amdgcn_global_load_lds(
        (const __attribute__((address_space(1))) unsigned int*)(const void*)g,
        (__attribute__((address_space(3))) unsigned int*)(void*)l,
        16, 0, 0);
}

// ---- R11: K-major PACKED staging layout -------------------------------------
// packed[(p*NKC + kc)*4096 + (r*4 + cs)*8 + e]  (shorts), where
//   p  = row panel (128 rows), kc = 32-element K-chunk, r = row & 127,
//   cs = chunk ^ ((r>>1)&3)  -- the R10 bank-conflict swizzle BAKED IN,
//   so LDS contents after staging are bit-identical to R10 and the
//   ds_read-side XOR (lgx) is unchanged.
// Each (p,kc) block is 8 KB CONTIGUOUS: one K-step's operand tile becomes a
// purely sequential stream (idx*16B, idx=0..511) instead of 128 scattered
// 64B lines at 1536/1024B stride -- the single variable this round tests.
template <int NKC>
__device__ inline void stage_packed(const unsigned short* __restrict__ P,
                                    unsigned short* sA, unsigned short* sB,
                                    int pi, int pj, int s, int t) {
    const unsigned short* bi = P + ((size_t)(pi * NKC + s) << 12);
    const unsigned short* bj = P + ((size_t)(pj * NKC + s) << 12);
    #pragma unroll
    for (int h = 0; h < 2; ++h) {
        const int idx = t + h * 256;        // 0..511; fully sequential stream
        gl2lds16(bi + idx * 8, &sA[idx * 8]);
        gl2lds16(bj + idx * 8, &sB[idx * 8]);
    }
}

// bid -> (ti, tj): chunked XCD swizzle + SUPER-BLOCK enumeration (R8/R10,
// proven FETCH win). 8x8 super-blocks; diagonal SBs 36 tiles, off-diag 64.
__device__ inline void tile_coords(int bid, int& ti, int& tj) {
    int swb = (bid & 7) * (NTILE / 8) + (bid >> 3);   // contiguous per XCD
    int sti = 0, stj = 0;
    for (;;) {
        const int sz = (sti == stj) ? 36 : 64;
        if (swb < sz) break;
        swb -= sz;
        if (++stj == 8) { ++sti; stj = sti; }
    }
    int i, j;
    if (sti == stj) {            // triangular SB: row i has 8-i tiles (j >= i)
        i = 0;
        while (swb >= 8 - i) { swb -= 8 - i; ++i; }
        j = i + swb;
    } else {                     // full SB: row-major 8x8
        i = swb >> 3;
        j = swb & 7;
    }
    ti = sti * 8 + i;
    tj = stj * 8 + j;
}

// ---------------- row-normalize fp32 -> bf16 INTO PACKED LAYOUT ---------------
// One wave per row; single pass (loads cached in registers). Writes go to the
// packed layout directly: each 8-lane group emits one full 64B line (the four
// 16B units of a (row, kc) span, internally permuted by the baked swizzle).
__global__ void norm_kernel(const float* __restrict__ Tg,
                            const float* __restrict__ Mo,
                            unsigned short* __restrict__ Pt,
                            unsigned short* __restrict__ Po,
                            float* __restrict__ zero_me) {
    if (blockIdx.x == 0 && threadIdx.x == 0) zero_me[0] = 0.0f;
    int bid = blockIdx.x;
    const float* X; unsigned short* Pk; int D, NKC;
    if (bid < N / 4) { X = Tg; Pk = Pt; D = DT; NKC = NKT; }
    else             { bid -= N / 4; X = Mo; Pk = Po; D = DO; NKC = NKO; }
    const int row  = bid * 4 + (threadIdx.x >> 6);
    const int lane = threadIdx.x & 63;
    const int nch  = D >> 8;                       // 3 (DT) or 2 (DO)
    const int r    = row & 127;                    // row within panel
    const int p    = row >> 7;                     // panel index
    const int key  = (r >> 1) & 3;                 // baked swizzle key
    const float* xr = X + (size_t)row * D;
    floatx4 vc[3];
    float ss = 0.0f;
    #pragma unroll
    for (int h = 0; h < 3; ++h) {
        if (h < nch) {
            vc[h] = *(const floatx4*)(xr + lane * 4 + h * 256);
            ss += vc[h][0] * vc[h][0] + vc[h][1] * vc[h][1]
                + vc[h][2] * vc[h][2] + vc[h][3] * vc[h][3];
        }
    }
    #pragma unroll
    for (int m = 32; m >= 1; m >>= 1) ss += __shfl_xor(ss, m);
    const float scale = 1.0f / fmaxf(sqrtf(ss), 1e-8f);
    #pragma unroll
    for (int h = 0; h < 3; ++h) {
        if (h < nch) {
            us4 o;
            #pragma unroll
            for (int j = 0; j < 4; ++j) o.x[j] = f2bf(vc[h][j] * scale);
            const int k0  = lane * 4 + h * 256;    // element index in row
            const int kc  = k0 >> 5;               // 32-element K-chunk
            const int ch  = (k0 >> 3) & 3;         // 16B unit within chunk
            const int cs  = ch ^ key;              // baked swizzle
            const int pos = (k0 >> 2) & 1;         // 8B half of the unit
            const size_t a = ((size_t)(p * NKC + kc) << 12)
                           + (size_t)(r * 4 + cs) * 8 + pos * 4;
            *(us4*)(Pk + a) = o;
        }
    }
}

// ---------------- fused dual-GEMM + softmax-stat tile kernel (R10 structure) ---
// Symmetric-tile scheme (ti <= tj): row-sums (lr-reduce) -> slot tj*2+wn;
// col-sums (lg-reduce) -> slot ti*2+wm. Per row, slots 0..127 written once.
// W = e3 parked bf16 in LDS sW[idx][t] (per-thread private, conflict-free).
// 48 KB LDS -> 3 blocks/CU, 84 VGPR. 2-barrier full-drain K-step cadence.
// ONLY change vs R10: staging reads the contiguous packed layout.
__launch_bounds__(256, 3)
__global__ void fused_kernel(const unsigned short* __restrict__ Pt,
                             const unsigned short* __restrict__ Po,
                             float* __restrict__ partials) {
    __shared__ unsigned short sA[BM * 32];     // 8 KB
    __shared__ unsigned short sB[BN * 32];     // 8 KB
    __shared__ unsigned short sW[64 * 256];    // 32 KB: [idx 0..63][thread 0..255]

    const int t    = threadIdx.x;
    const int lane = t & 63;
    const int w    = t >> 6;
    const int wm   = w >> 1, wn = w & 1;
    const int lr   = lane & 15, lg = lane >> 4;
    const int lgx  = lg ^ ((lr >> 1) & 3);     // swizzled read chunk index

    int ti, tj; tile_coords(blockIdx.x, ti, tj);
    const bool offdiag = (ti != tj);
    const int i0 = ti * BM, j0 = tj * BN;

    floatx4 acc[4][4];
    #pragma unroll
    for (int a = 0; a < 4; ++a)
        #pragma unroll
        for (int b = 0; b < 4; ++b)
            acc[a][b] = (floatx4){0.0f, 0.0f, 0.0f, 0.0f};

    // ---- teacher GEMM: S_t tile, 24 K-chunks ----
    for (int s = 0; s < NKT; ++s) {
        stage_packed<NKT>(Pt, sA, sB, ti, tj, s, t);
        asm volatile("s_waitcnt vmcnt(0)" ::: "memory");
        __syncthreads();
        short8 af[4], bf[4];
        #pragma unroll
        for (int mi = 0; mi < 4; ++mi)
            af[mi] = *(const short8*)&sA[(wm * 64 + mi * 16 + lr) * 32 + (lgx << 3)];
        #pragma unroll
        for (int ni = 0; ni < 4; ++ni)
            bf[ni] = *(const short8*)&sB[(wn * 64 + ni * 16 + lr) * 32 + (lgx << 3)];
        #pragma unroll
        for (int mi = 0; mi < 4; ++mi)
            #pragma unroll
            for (int ni = 0; ni < 4; ++ni)
                acc[mi][ni] = __builtin_amdgcn_mfma_f32_16x16x32_bf16(
                    af[mi], bf[ni], acc[mi][ni], 0, 0, 0);
        __syncthreads();
    }

    // ---- teacher epilogue: Zt, V, Sum(e3*a) per row (both orientations);
    //      park W=e3 (bf16) in LDS. C/D layout: col=lane&15, row=(lane>>4)*4+reg
    {
        float czt[4], cvv[4], cua[4];
        #pragma unroll
        for (int ni = 0; ni < 4; ++ni) { czt[ni] = 0.0f; cvv[ni] = 0.0f; cua[ni] = 0.0f; }
        #pragma unroll
        for (int mi = 0; mi < 4; ++mi) {
            #pragma unroll
            for (int r = 0; r < 4; ++r) {
                const int row = wm * 64 + mi * 16 + lg * 4 + r;
                const int gi  = i0 + row;
                float zt = 0.0f, vv = 0.0f, ua = 0.0f;
                #pragma unroll
                for (int ni = 0; ni < 4; ++ni) {
                    const int gj = j0 + wn * 64 + ni * 16 + lr;
                    const float a = acc[mi][ni][r];
                    float ea = __expf(a - 1.0f);
                    if (gi == gj) ea = 0.0f;               // diagonal -> prob 0
                    const float e3 = ea * ea * ea;
                    zt += ea; vv += e3; ua += e3 * a;
                    czt[ni] += ea; cvv[ni] += e3; cua[ni] += e3 * a;
                    sW[(mi * 16 + ni * 4 + r) * 256 + t] = f2bf(e3);
                }
                #pragma unroll
                for (int m = 8; m >= 1; m >>= 1) {
                    zt += __shfl_xor(zt, m);
                    vv += __shfl_xor(vv, m);
                    ua += __shfl_xor(ua, m);
                }
                if (lr == 0) {
                    const size_t base = (size_t)(tj * 2 + wn) * N + gi;
                    partials[0 * PL + base] = zt;
                    partials[1 * PL + base] = vv;
                    partials[2 * PL + base] = ua;
                }
            }
        }
        if (offdiag) {
            #pragma unroll
            for (int ni = 0; ni < 4; ++ni) {
                #pragma unroll
                for (int m = 16; m <= 32; m <<= 1) {
                    czt[ni] += __shfl_xor(czt[ni], m);
                    cvv[ni] += __shfl_xor(cvv[ni], m);
                    cua[ni] += __shfl_xor(cua[ni], m);
                }
            }
            if (lg == 0) {
                #pragma unroll
                for (int ni = 0; ni < 4; ++ni) {
                    const int gj = j0 + wn * 64 + ni * 16 + lr;   // contiguous in lr
                    const size_t base = (size_t)(ti * 2 + wm) * N + gj;
                    partials[0 * PL + base] = czt[ni];
                    partials[1 * PL + base] = cvv[ni];
                    partials[2 * PL + base] = cua[ni];
                }
            }
        }
    }
    // No barrier needed: sW is per-thread private; sA/sB free to restage
    // (all reads of the last teacher tile completed before the final barrier).

    // ---- student GEMM: S_o tile, 16 K-chunks (same accumulator registers) ----
    #pragma unroll
    for (int a = 0; a < 4; ++a)
        #pragma unroll
        for (int b = 0; b < 4; ++b)
            acc[a][b] = (floatx4){0.0f, 0.0f, 0.0f, 0.0f};

    for (int s = 0; s < NKO; ++s) {
        stage_packed<NKO>(Po, sA, sB, ti, tj, s, t);
        asm volatile("s_waitcnt vmcnt(0)" ::: "memory");
        __syncthreads();
        short8 af[4], bf[4];
        #pragma unroll
        for (int mi = 0; mi < 4; ++mi)
            af[mi] = *(const short8*)&sA[(wm * 64 + mi * 16 + lr) * 32 + (lgx << 3)];
        #pragma unroll
        for (int ni = 0; ni < 4; ++ni)
            bf[ni] = *(const short8*)&sB[(wn * 64 + ni * 16 + lr) * 32 + (lgx << 3)];
        #pragma unroll
        for (int mi = 0; mi < 4; ++mi)
            #pragma unroll
            for (int ni = 0; ni < 4; ++ni)
                acc[mi][ni] = __builtin_amdgcn_mfma_f32_16x16x32_bf16(
                    af[mi], bf[ni], acc[mi][ni], 0, 0, 0);
        __syncthreads();
    }

    // ---- final epilogue: Zo, Sum(W*b) per row (both orientations) ----
    {
        float czo[4], cwb[4];
        #pragma unroll
        for (int ni = 0; ni < 4; ++ni) { czo[ni] = 0.0f; cwb[ni] = 0.0f; }
        #pragma unroll
        for (int mi = 0; mi < 4; ++mi) {
            #pragma unroll
            for (int r = 0; r < 4; ++r) {
                const int row = wm * 64 + mi * 16 + lg * 4 + r;
                const int gi  = i0 + row;
                float zo = 0.0f, wb = 0.0f;
                #pragma unroll
                for (int ni = 0; ni < 4; ++ni) {
                    const int gj = j0 + wn * 64 + ni * 16 + lr;
                    const float b = acc[mi][ni][r];
                    float eb = __expf(b - 1.0f);
                    if (gi == gj) eb = 0.0f;
                    const float wgt = bf2f(sW[(mi * 16 + ni * 4 + r) * 256 + t]);
                    zo += eb; wb += wgt * b;   // diag: W==0 -> no contribution
                    czo[ni] += eb; cwb[ni] += wgt * b;
                }
                #pragma unroll
                for (int m = 8; m >= 1; m >>= 1) {
                    zo += __shfl_xor(zo, m);
                    wb += __shfl_xor(wb, m);
                }
                if (lr == 0) {
                    const size_t base = (size_t)(tj * 2 + wn) * N + gi;
                    partials[3 * PL + base] = zo;
                    partials[4 * PL + base] = wb;
                }
            }
        }
        if (offdiag) {
            #pragma unroll
            for (int ni = 0; ni < 4; ++ni) {
                #pragma unroll
                for (int m = 16; m <= 32; m <<= 1) {
                    czo[ni] += __shfl_xor(czo[ni], m);
                    cwb[ni] += __shfl_xor(cwb[ni], m);
                }
            }
            if (lg == 0) {
                #pragma unroll
                for (int ni = 0; ni < 4; ++ni) {
                    const int gj = j0 + wn * 64 + ni * 16 + lr;   // contiguous in lr
                    const size_t base = (size_t)(ti * 2 + wm) * N + gj;
                    partials[3 * PL + base] = czo[ni];
                    partials[4 * PL + base] = cwb[ni];
                }
            }
        }
    }
}

// ---------------- final per-row combine + scalar reduce ----------------
// 128 blocks; each block: 64 rows, 4 waves split the 128 slots (32 each),
// LDS combine, wave 0 computes per-row loss + block partial -> one atomic.
__global__ void reduce_kernel(const float* __restrict__ partials,
                              float* __restrict__ out) {
    __shared__ float sh[5][256];
    const int t    = threadIdx.x;
    const int lane = t & 63;
    const int g    = t >> 6;
    const int i    = blockIdx.x * 64 + lane;      // row (coalesced across lanes)
    float s[5] = {0.0f, 0.0f, 0.0f, 0.0f, 0.0f};
    for (int jb = g * (NSLOT / 4); jb < (g + 1) * (NSLOT / 4); ++jb) {
        const size_t base = (size_t)jb * N + i;
        #pragma unroll
        for (int p = 0; p < 5; ++p) s[p] += partials[p * PL + base];
    }
    #pragma unroll
    for (int p = 0; p < 5; ++p) sh[p][t] = s[p];
    __syncthreads();
    if (g == 0) {
        float v[5];
        #pragma unroll
        for (int p = 0; p < 5; ++p)
            v[p] = sh[p][lane] + sh[p][64 + lane] + sh[p][128 + lane] + sh[p][192 + lane];
        // loss_i = (UA - WB + V*log(Zo/Zt)) / Zt^3
        float li = (v[2] - v[4] + v[1] * __logf(v[3] / v[0])) / (v[0] * v[0] * v[0]);
        #pragma unroll
        for (int m = 32; m >= 1; m >>= 1) li += __shfl_xor(li, m);
        if (lane == 0)
            atomicAdd(out, li * (1.0f / ((float)N * (float)N)));   // WEIGHT=1
    }
}

extern "C" void kernel_launch(void* const* d_in, const int* in_sizes, int n_in,
                              void* d_out, int out_size, void* d_ws, size_t ws_size,
                              hipStream_t stream) {
    (void)in_sizes; (void)n_in; (void)out_size; (void)ws_size;
    const float* mo = (const float*)d_in[0];   // model_output [8192,512] fp32
    const float* tg = (const float*)d_in[1];   // targets      [8192,768] fp32
    float* out = (float*)d_out;

    char* ws = (char*)d_ws;
    unsigned short* Pt = (unsigned short*)ws;                          // 12.58 MB packed
    unsigned short* Po = (unsigned short*)(ws + (size_t)N * DT * 2);   //  8.39 MB packed
    float* partials    = (float*)(ws + (size_t)N * DT * 2 + (size_t)N * DO * 2);
    // partials: 5 planes * 128 * 8192 * 4 B = 20.97 MB; total ws use ~41.9 MB

    norm_kernel<<<2 * (N / 4), 256, 0, stream>>>(tg, mo, Pt, Po, out);  // also zeroes out
    fused_kernel<<<NTILE, 256, 0, stream>>>(Pt, Po, partials);
    reduce_kernel<<<N / 64, 256, 0, stream>>>(partials, out);
}